// Round 8
// baseline (807.199 us; speedup 1.0000x reference)
//
#include <hip/hip_runtime.h>
#include <hip/hip_fp16.h>
#include <math.h>

typedef _Float16 half_t;
typedef half_t half4_t __attribute__((ext_vector_type(4)));
typedef half_t half8_t __attribute__((ext_vector_type(8)));
typedef float f32x4 __attribute__((ext_vector_type(4)));

#define LN_EPS 1e-5f

// ---------------------------------------------------------------------------
// Pack W*g (LN gain folded) into f16 MFMA B-fragment order:
//   packed[((cbg*T + t)*64 + l)*8 + j] = (f16)(W[16*cbg+(l&15)][32t+8*(l>>4)+j] * g[k])
// ---------------------------------------------------------------------------
__global__ void pack_weights(const float* __restrict__ W0, const float* __restrict__ g0,
                             const float* __restrict__ W1, const float* __restrict__ g1,
                             const float* __restrict__ W2, const float* __restrict__ g2,
                             half_t* __restrict__ ws) {
    int sid = blockIdx.x * 256 + threadIdx.x;
    const float* W; const float* g; int K, T, off;
    if (sid < 49152)      { W = W0; g = g0; K = 768; T = 24; off = 0; }
    else if (sid < 65536) { W = W1; g = g1; K = 512; T = 16; off = 49152; sid -= 49152; }
    else if (sid < 69632) { W = W2; g = g2; K = 256; T = 8;  off = 65536; sid -= 65536; }
    else return;
    const int l   = sid & 63;
    const int t   = (sid >> 6) % T;
    const int cbg = (sid >> 6) / T;
    const int n   = (l & 15) + 16 * cbg;
    const int k0  = 32 * t + 8 * (l >> 4);
    const float* src = W + (size_t)n * K + k0;
    const float* gs  = g + k0;
    half8_t v;
    #pragma unroll
    for (int jq = 0; jq < 8; jq++) v[jq] = (half_t)(src[jq] * gs[jq]);
    *(half8_t*)(ws + (size_t)(off + sid) * 8) = v;
}

// ---------------------------------------------------------------------------
// Fold LN bias into per-output scalars: s[n]=sum_k W[n,k]*g[k],
// c'[n]=sum_k W[n,k]*b[k]+c[n]. f layout:
// s0[512] c0[512] s1[256] c1[256] s2[128] c2[128] w3g[128] s3 c3'
// ---------------------------------------------------------------------------
__global__ void fold_bias(const float* __restrict__ W0, const float* __restrict__ g0,
                          const float* __restrict__ b0, const float* __restrict__ c0,
                          const float* __restrict__ W1, const float* __restrict__ g1,
                          const float* __restrict__ b1, const float* __restrict__ c1,
                          const float* __restrict__ W2, const float* __restrict__ g2,
                          const float* __restrict__ b2, const float* __restrict__ c2,
                          const float* __restrict__ W3, const float* __restrict__ g3,
                          const float* __restrict__ b3, const float* __restrict__ c3,
                          float* __restrict__ f) {
    const int gw   = (blockIdx.x * 256 + threadIdx.x) >> 6;
    const int lane = threadIdx.x & 63;
    if (gw == 896) {
        float s = 0.f, cb_ = 0.f;
        for (int k = lane; k < 128; k += 64) {
            const float wg = W3[k] * g3[k];
            f[1792 + k] = wg;
            s += wg; cb_ += W3[k] * b3[k];
        }
        #pragma unroll
        for (int m = 1; m < 64; m <<= 1) { s += __shfl_xor(s, m); cb_ += __shfl_xor(cb_, m); }
        if (lane == 0) { f[1920] = s; f[1921] = cb_ + c3[0]; }
        return;
    }
    const float *W, *g, *b, *cc; int K, n; float *sf, *cf;
    if (gw < 512)      { W = W0; g = g0; b = b0; cc = c0; K = 768; n = gw;       sf = f;        cf = f + 512; }
    else if (gw < 768) { W = W1; g = g1; b = b1; cc = c1; K = 512; n = gw - 512; sf = f + 1024; cf = f + 1280; }
    else if (gw < 896) { W = W2; g = g2; b = b2; cc = c2; K = 256; n = gw - 768; sf = f + 1536; cf = f + 1664; }
    else return;
    const float* Wr = W + (size_t)n * K;
    float s = 0.f, cb_ = 0.f;
    for (int k = lane; k < K; k += 64) { const float wg = Wr[k] * g[k]; s += wg; cb_ += Wr[k] * b[k]; }
    #pragma unroll
    for (int m = 1; m < 64; m <<= 1) { s += __shfl_xor(s, m); cb_ += __shfl_xor(cb_, m); }
    if (lane == 0) { sf[n] = s; cf[n] = cb_ + cc[n]; }
}

// ---------------------------------------------------------------------------
// Fused MLP v8 = R6 structure with 2(rows)x4(cols) wave grid in ALL GEMMs:
// A-fragment LDS redundancy 8x -> 2x (DS-pipe de-saturation in GEMM phases),
// W L2 traffic 2x (within budget). Staging/scans/LN identical to R6.
// ---------------------------------------------------------------------------
__global__ __launch_bounds__(512, 4)
void fused_mlp(const float* __restrict__ x_in,
               const half_t* __restrict__ W0p, const half_t* __restrict__ W1p,
               const half_t* __restrict__ W2p, const float* __restrict__ f,
               float* __restrict__ out)
{
    __shared__ half_t frag[32768];       // 64 KiB: staging aliases [0,16384); x1 full; x2 [0,16K); y3 [0,8.5K)
    __shared__ float row_m[64], row_rs[64];
    __shared__ float w3s[128];

    const int tid  = threadIdx.x;
    const int lane = tid & 63;
    const int wv   = tid >> 6;       // wave 0..7
    const int grp  = lane >> 4;
    const int cl   = lane & 15;
    const int row  = tid >> 3;       // 0..63 (staging/scan row)
    const int jj   = tid & 7;        // 8 threads per row
    const int rbw  = row >> 4;
    const long r0  = (long)blockIdx.x * 64;
    const float* xrow = x_in + (r0 + row) * 768;

    const int h  = wv >> 2;          // row half: rows 32h..32h+32
    const int q  = wv & 3;           // col group

    const float* s0f = f;        const float* c0f = f + 512;
    const float* s1f = f + 1024; const float* c1f = f + 1280;
    const float* s2f = f + 1536; const float* c2f = f + 1664;

    if (tid < 128) w3s[tid] = f[1792 + tid];    // folded W3*g3

    float s = 0.f, ss = 0.f;
    f32x4 vb[4];

    auto stage_load = [&](int c) {
        const float* xp = xrow + 128 * c + 4 * jj;
        #pragma unroll
        for (int i = 0; i < 4; i++)
            vb[i] = __builtin_nontemporal_load((const f32x4*)(xp + 32 * i));
    };
    auto stage_write = [&](int c) {
        half_t* fb = frag + 8192 * (c & 1);
        const int hg = jj >> 1, jo = 4 * (jj & 1);
        #pragma unroll
        for (int i = 0; i < 4; i++) {
            const f32x4 v = vb[i];
            s  += v[0] + v[1] + v[2] + v[3];
            ss += v[0]*v[0] + v[1]*v[1] + v[2]*v[2] + v[3]*v[3];
            half4_t hv;
            hv[0] = (half_t)v[0]; hv[1] = (half_t)v[1];
            hv[2] = (half_t)v[2]; hv[3] = (half_t)v[3];
            *(half4_t*)(&fb[((i * 4 + rbw) * 64 + ((row & 15) + 16 * hg)) * 8 + jo]) = hv;
        }
    };

    // acc0: 2 row-blocks x 8 col-blocks (wave covers 32 rows x 128 cols)
    f32x4 acc0[2][8];
    #pragma unroll
    for (int rb = 0; rb < 2; rb++)
        #pragma unroll
        for (int cb = 0; cb < 8; cb++) acc0[rb][cb] = 0.f;

    // GEMM0 chunk: 4 t-steps; A 2 frags/t (rows 32h..), B 8 frags/t from L2
    auto gemm0 = [&](int c) {
        const half_t* fb = frag + 8192 * (c & 1);
        const half_t* wq = W0p + (size_t)(8 * q) * 12288 + (size_t)(4 * c) * 512 + lane * 8;
        #pragma unroll
        for (int tt = 0; tt < 4; tt++) {
            half8_t af[2];
            #pragma unroll
            for (int rb = 0; rb < 2; rb++)
                af[rb] = *(const half8_t*)(&fb[((tt * 4 + 2 * h + rb) * 64 + lane) * 8]);
            #pragma unroll
            for (int cb = 0; cb < 8; cb++) {
                const half8_t bf = *(const half8_t*)(wq + (size_t)cb * 12288 + tt * 512);
                acc0[0][cb] = __builtin_amdgcn_mfma_f32_16x16x32_f16(af[0], bf, acc0[0][cb], 0, 0, 0);
                acc0[1][cb] = __builtin_amdgcn_mfma_f32_16x16x32_f16(af[1], bf, acc0[1][cb], 0, 0, 0);
            }
        }
    };

    // ---- layer-0 pipeline: 6 chunks of K=128 ----
    stage_load(0); stage_write(0);
    __syncthreads();
    #pragma unroll 1
    for (int c = 0; c < 6; c++) {
        if (c < 5) stage_load(c + 1);
        gemm0(c);
        if (c < 5) stage_write(c + 1);
        if (c == 4) {
            s  += __shfl_xor(s, 1);  s  += __shfl_xor(s, 2);  s  += __shfl_xor(s, 4);
            ss += __shfl_xor(ss, 1); ss += __shfl_xor(ss, 2); ss += __shfl_xor(ss, 4);
            if (jj == 0) {
                const float mm = s * (1.f / 768.f);
                row_m[row]  = mm;
                row_rs[row] = 1.f / sqrtf(ss * (1.f / 768.f) - mm * mm + LN_EPS);
            }
        }
        __syncthreads();
    }

    // ---- epilogue0: LN0 fold + ELU + write x1 fragments ----
    {
        float sv[8], cv[8];
        #pragma unroll
        for (int cb = 0; cb < 8; cb++) {
            const int c = cl + 16 * (8 * q + cb);
            sv[cb] = s0f[c]; cv[cb] = c0f[c];
        }
        #pragma unroll
        for (int rb = 0; rb < 2; rb++)
            #pragma unroll
            for (int v = 0; v < 4; v++) {
                const int r = 32 * h + 16 * rb + 4 * grp + v;
                const float rm = row_m[r], rr = row_rs[r];
                #pragma unroll
                for (int cb = 0; cb < 8; cb++) {
                    float y = rr * (acc0[rb][cb][v] - rm * sv[cb]) + cv[cb];
                    y = y > 0.f ? y : (__expf(y) - 1.f);
                    const int c = cl + 16 * (8 * q + cb);
                    frag[(((c >> 5) * 4 + (2 * h + rb)) * 64 + (4 * grp + v + 16 * ((c >> 3) & 3))) * 8 + (c & 7)] = (half_t)y;
                }
            }
    }
    __syncthreads();

    // ---- LN1 stats: LDS scan of x1 (512 cols, 8 threads/row, 8 chunks) ----
    {
        const int r15 = row & 15, rb = row >> 4;
        float s_ = 0.f, q_ = 0.f;
        #pragma unroll
        for (int i = 0; i < 8; i++) {
            const int ch = jj + 8 * i;
            const int t = ch >> 2, cg = ch & 3;
            const half8_t hh = *(const half8_t*)(frag + (size_t)((t * 4 + rb) * 64 + r15 + 16 * cg) * 8);
            #pragma unroll
            for (int e = 0; e < 8; e++) { const float fv = (float)hh[e]; s_ += fv; q_ += fv * fv; }
        }
        s_ += __shfl_xor(s_, 1); s_ += __shfl_xor(s_, 2); s_ += __shfl_xor(s_, 4);
        q_ += __shfl_xor(q_, 1); q_ += __shfl_xor(q_, 2); q_ += __shfl_xor(q_, 4);
        if (jj == 0) {
            const float mm = s_ * (1.f / 512.f);
            row_m[row]  = mm;
            row_rs[row] = 1.f / sqrtf(q_ * (1.f / 512.f) - mm * mm + LN_EPS);
        }
    }

    // ---- GEMM1: K=512 (16 t-steps); wave = 32 rows x 64 cols, B dbuf ----
    f32x4 acc1[2][4];
    #pragma unroll
    for (int rb = 0; rb < 2; rb++)
        #pragma unroll
        for (int cb = 0; cb < 4; cb++) acc1[rb][cb] = 0.f;
    {
        const half_t* wp = W1p + (size_t)(4 * q) * 8192 + lane * 8;   // + cb*8192 + t*512
        half8_t bA[4], bB[4];
        #pragma unroll
        for (int cb = 0; cb < 4; cb++) bA[cb] = *(const half8_t*)(wp + (size_t)cb * 8192);
        #pragma unroll
        for (int t = 0; t < 16; t++) {
            half8_t* cur = (t & 1) ? bB : bA;
            half8_t* nxt = (t & 1) ? bA : bB;
            if (t < 15) {
                #pragma unroll
                for (int cb = 0; cb < 4; cb++)
                    nxt[cb] = *(const half8_t*)(wp + (size_t)cb * 8192 + (t + 1) * 512);
            }
            half8_t af[2];
            #pragma unroll
            for (int rb = 0; rb < 2; rb++)
                af[rb] = *(const half8_t*)(&frag[((t * 4 + 2 * h + rb) * 64 + lane) * 8]);
            #pragma unroll
            for (int cb = 0; cb < 4; cb++) {
                acc1[0][cb] = __builtin_amdgcn_mfma_f32_16x16x32_f16(af[0], cur[cb], acc1[0][cb], 0, 0, 0);
                acc1[1][cb] = __builtin_amdgcn_mfma_f32_16x16x32_f16(af[1], cur[cb], acc1[1][cb], 0, 0, 0);
            }
        }
    }
    __syncthreads();   // gemm1 + scan reads done; stats visible

    // ---- epilogue1: LN1 fold + ELU + write x2 fragments ----
    {
        float sv[4], cv[4];
        #pragma unroll
        for (int cb = 0; cb < 4; cb++) {
            const int c = cl + 16 * (4 * q + cb);
            sv[cb] = s1f[c]; cv[cb] = c1f[c];
        }
        #pragma unroll
        for (int rb = 0; rb < 2; rb++)
            #pragma unroll
            for (int v = 0; v < 4; v++) {
                const int r = 32 * h + 16 * rb + 4 * grp + v;
                const float rm = row_m[r], rr = row_rs[r];
                #pragma unroll
                for (int cb = 0; cb < 4; cb++) {
                    float y = rr * (acc1[rb][cb][v] - rm * sv[cb]) + cv[cb];
                    y = y > 0.f ? y : (__expf(y) - 1.f);
                    const int c = cl + 16 * (4 * q + cb);
                    frag[(((c >> 5) * 4 + (2 * h + rb)) * 64 + (4 * grp + v + 16 * ((c >> 3) & 3))) * 8 + (c & 7)] = (half_t)y;
                }
            }
    }
    __syncthreads();

    // ---- LN2 stats: LDS scan of x2 (256 cols, 8 threads/row, 4 chunks) ----
    {
        const int r15 = row & 15, rb = row >> 4;
        float s_ = 0.f, q_ = 0.f;
        #pragma unroll
        for (int i = 0; i < 4; i++) {
            const int ch = jj + 8 * i;
            const int t = ch >> 2, cg = ch & 3;
            const half8_t hh = *(const half8_t*)(frag + (size_t)((t * 4 + rb) * 64 + r15 + 16 * cg) * 8);
            #pragma unroll
            for (int e = 0; e < 8; e++) { const float fv = (float)hh[e]; s_ += fv; q_ += fv * fv; }
        }
        s_ += __shfl_xor(s_, 1); s_ += __shfl_xor(s_, 2); s_ += __shfl_xor(s_, 4);
        q_ += __shfl_xor(q_, 1); q_ += __shfl_xor(q_, 2); q_ += __shfl_xor(q_, 4);
        if (jj == 0) {
            const float mm = s_ * (1.f / 256.f);
            row_m[row]  = mm;
            row_rs[row] = 1.f / sqrtf(q_ * (1.f / 256.f) - mm * mm + LN_EPS);
        }
    }

    // ---- GEMM2: K=256 (8 t-steps); wave = 32 rows x 32 cols ----
    f32x4 acc2[2][2];
    acc2[0][0] = 0.f; acc2[0][1] = 0.f; acc2[1][0] = 0.f; acc2[1][1] = 0.f;
    {
        const half_t* wp = W2p + (size_t)(2 * q) * 4096 + lane * 8;   // + cb*4096 + t*512
        half8_t bA[2];
        bA[0] = *(const half8_t*)(wp);
        bA[1] = *(const half8_t*)(wp + 4096);
        #pragma unroll
        for (int t = 0; t < 8; t++) {
            const half8_t c0_ = bA[0], c1_ = bA[1];
            if (t < 7) {
                bA[0] = *(const half8_t*)(wp + (t + 1) * 512);
                bA[1] = *(const half8_t*)(wp + 4096 + (t + 1) * 512);
            }
            half8_t af[2];
            #pragma unroll
            for (int rb = 0; rb < 2; rb++)
                af[rb] = *(const half8_t*)(&frag[((t * 4 + 2 * h + rb) * 64 + lane) * 8]);
            acc2[0][0] = __builtin_amdgcn_mfma_f32_16x16x32_f16(af[0], c0_, acc2[0][0], 0, 0, 0);
            acc2[1][0] = __builtin_amdgcn_mfma_f32_16x16x32_f16(af[1], c0_, acc2[1][0], 0, 0, 0);
            acc2[0][1] = __builtin_amdgcn_mfma_f32_16x16x32_f16(af[0], c1_, acc2[0][1], 0, 0, 0);
            acc2[1][1] = __builtin_amdgcn_mfma_f32_16x16x32_f16(af[1], c1_, acc2[1][1], 0, 0, 0);
        }
    }
    __syncthreads();   // gemm2 + scan2 reads done

    // ---- epilogue2: LN2 fold + ELU -> y3 tile [64][136] in LDS ----
    {
        #pragma unroll
        for (int cb = 0; cb < 2; cb++) {
            const int c2i = cl + 16 * (2 * q + cb);
            const float sv = s2f[c2i], cv = c2f[c2i];
            #pragma unroll
            for (int rb = 0; rb < 2; rb++)
                #pragma unroll
                for (int v = 0; v < 4; v++) {
                    const int r = 32 * h + 16 * rb + 4 * grp + v;
                    const float rm = row_m[r], rr = row_rs[r];
                    float y = rr * (acc2[rb][cb][v] - rm * sv) + cv;
                    y = y > 0.f ? y : (__expf(y) - 1.f);
                    frag[r * 136 + c2i] = (half_t)y;
                }
        }
    }
    __syncthreads();

    // ---- LN3 scan + folded W3 dot + output (8 threads/row, 16 cols each) ----
    {
        float s_ = 0.f, q_ = 0.f, d_ = 0.f;
        #pragma unroll
        for (int u = 0; u < 2; u++) {
            const int cb = jj * 16 + 8 * u;
            const half8_t hh = *(const half8_t*)(frag + row * 136 + cb);
            #pragma unroll
            for (int e = 0; e < 8; e++) {
                const float fv = (float)hh[e];
                s_ += fv; q_ += fv * fv; d_ += fv * w3s[cb + e];
            }
        }
        s_ += __shfl_xor(s_, 1); s_ += __shfl_xor(s_, 2); s_ += __shfl_xor(s_, 4);
        q_ += __shfl_xor(q_, 1); q_ += __shfl_xor(q_, 2); q_ += __shfl_xor(q_, 4);
        d_ += __shfl_xor(d_, 1); d_ += __shfl_xor(d_, 2); d_ += __shfl_xor(d_, 4);
        if (jj == 0) {
            const float mm = s_ * (1.f / 128.f);
            const float rs = 1.f / sqrtf(q_ * (1.f / 128.f) - mm * mm + LN_EPS);
            out[r0 + row] = rs * (d_ - mm * f[1920]) + f[1921];
        }
    }
}

extern "C" void kernel_launch(void* const* d_in, const int* in_sizes, int n_in,
                              void* d_out, int out_size, void* d_ws, size_t ws_size,
                              hipStream_t stream) {
    const float* x  = (const float*)d_in[0];
    const float* g0 = (const float*)d_in[1];
    const float* b0 = (const float*)d_in[2];
    const float* W0 = (const float*)d_in[3];
    const float* c0 = (const float*)d_in[4];
    const float* g1 = (const float*)d_in[5];
    const float* b1 = (const float*)d_in[6];
    const float* W1 = (const float*)d_in[7];
    const float* c1 = (const float*)d_in[8];
    const float* g2 = (const float*)d_in[9];
    const float* b2 = (const float*)d_in[10];
    const float* W2 = (const float*)d_in[11];
    const float* c2 = (const float*)d_in[12];
    const float* g3 = (const float*)d_in[13];
    const float* b3 = (const float*)d_in[14];
    const float* W3 = (const float*)d_in[15];
    const float* c3 = (const float*)d_in[16];

    half_t* ws = (half_t*)d_ws;            // packed weights: 557056 halves
    float*  f  = (float*)(ws + 557056);    // folded scalars: 1922 floats

    pack_weights<<<272, 256, 0, stream>>>(W0, g0, W1, g1, W2, g2, ws);
    fold_bias<<<225, 256, 0, stream>>>(W0, g0, b0, c0, W1, g1, b1, c1,
                                       W2, g2, b2, c2, W3, g3, b3, c3, f);

    const int nrows = in_sizes[0] / 768;   // 262144
    fused_mlp<<<nrows / 64, 512, 0, stream>>>(
        x, ws, ws + 393216, ws + 524288, f, (float*)d_out);
}

// Round 9
// 545.467 us; speedup vs baseline: 1.4798x; 1.4798x over previous
//
#include <hip/hip_runtime.h>
#include <hip/hip_fp16.h>
#include <math.h>

typedef _Float16 half_t;
typedef half_t half2_t __attribute__((ext_vector_type(2)));
typedef half_t half4_t __attribute__((ext_vector_type(4)));
typedef half_t half8_t __attribute__((ext_vector_type(8)));
typedef float f32x4 __attribute__((ext_vector_type(4)));

#define LN_EPS 1e-5f
#define FDOT2(a, b, c) __builtin_amdgcn_fdot2((a), (b), (c), false)

// ---------------------------------------------------------------------------
// Pack W*g (LN gain folded) into f16 MFMA B-fragment order:
//   packed[((cbg*T + t)*64 + l)*8 + j] = (f16)(W[16*cbg+(l&15)][32t+8*(l>>4)+j] * g[k])
// ---------------------------------------------------------------------------
__global__ void pack_weights(const float* __restrict__ W0, const float* __restrict__ g0,
                             const float* __restrict__ W1, const float* __restrict__ g1,
                             const float* __restrict__ W2, const float* __restrict__ g2,
                             half_t* __restrict__ ws) {
    int sid = blockIdx.x * 256 + threadIdx.x;
    const float* W; const float* g; int K, T, off;
    if (sid < 49152)      { W = W0; g = g0; K = 768; T = 24; off = 0; }
    else if (sid < 65536) { W = W1; g = g1; K = 512; T = 16; off = 49152; sid -= 49152; }
    else if (sid < 69632) { W = W2; g = g2; K = 256; T = 8;  off = 65536; sid -= 65536; }
    else return;
    const int l   = sid & 63;
    const int t   = (sid >> 6) % T;
    const int cbg = (sid >> 6) / T;
    const int n   = (l & 15) + 16 * cbg;
    const int k0  = 32 * t + 8 * (l >> 4);
    const float* src = W + (size_t)n * K + k0;
    const float* gs  = g + k0;
    half8_t v;
    #pragma unroll
    for (int jq = 0; jq < 8; jq++) v[jq] = (half_t)(src[jq] * gs[jq]);
    *(half8_t*)(ws + (size_t)(off + sid) * 8) = v;
}

// ---------------------------------------------------------------------------
// Fold LN bias into per-output scalars: s[n]=sum_k W[n,k]*g[k],
// c'[n]=sum_k W[n,k]*b[k]+c[n]. f layout:
// s0[512] c0[512] s1[256] c1[256] s2[128] c2[128] w3g[128] s3 c3'
// ---------------------------------------------------------------------------
__global__ void fold_bias(const float* __restrict__ W0, const float* __restrict__ g0,
                          const float* __restrict__ b0, const float* __restrict__ c0,
                          const float* __restrict__ W1, const float* __restrict__ g1,
                          const float* __restrict__ b1, const float* __restrict__ c1,
                          const float* __restrict__ W2, const float* __restrict__ g2,
                          const float* __restrict__ b2, const float* __restrict__ c2,
                          const float* __restrict__ W3, const float* __restrict__ g3,
                          const float* __restrict__ b3, const float* __restrict__ c3,
                          float* __restrict__ f) {
    const int gw   = (blockIdx.x * 256 + threadIdx.x) >> 6;
    const int lane = threadIdx.x & 63;
    if (gw == 896) {
        float s = 0.f, cb_ = 0.f;
        for (int k = lane; k < 128; k += 64) {
            const float wg = W3[k] * g3[k];
            f[1792 + k] = wg;
            s += wg; cb_ += W3[k] * b3[k];
        }
        #pragma unroll
        for (int m = 1; m < 64; m <<= 1) { s += __shfl_xor(s, m); cb_ += __shfl_xor(cb_, m); }
        if (lane == 0) { f[1920] = s; f[1921] = cb_ + c3[0]; }
        return;
    }
    const float *W, *g, *b, *cc; int K, n; float *sf, *cf;
    if (gw < 512)      { W = W0; g = g0; b = b0; cc = c0; K = 768; n = gw;       sf = f;        cf = f + 512; }
    else if (gw < 768) { W = W1; g = g1; b = b1; cc = c1; K = 512; n = gw - 512; sf = f + 1024; cf = f + 1280; }
    else if (gw < 896) { W = W2; g = g2; b = b2; cc = c2; K = 256; n = gw - 768; sf = f + 1536; cf = f + 1664; }
    else return;
    const float* Wr = W + (size_t)n * K;
    float s = 0.f, cb_ = 0.f;
    for (int k = lane; k < K; k += 64) { const float wg = Wr[k] * g[k]; s += wg; cb_ += Wr[k] * b[k]; }
    #pragma unroll
    for (int m = 1; m < 64; m <<= 1) { s += __shfl_xor(s, m); cb_ += __shfl_xor(cb_, m); }
    if (lane == 0) { sf[n] = s; cf[n] = cb_ + cc[n]; }
}

// ---------------------------------------------------------------------------
// Fused MLP v9 = R6 structure + conflict-free GEMM-style LN scans + fdot2
// stat accumulation (v_dot2_f32_f16) + packed-half2 W3 dot.
// ---------------------------------------------------------------------------
__global__ __launch_bounds__(512, 4)
void fused_mlp(const float* __restrict__ x_in,
               const half_t* __restrict__ W0p, const half_t* __restrict__ W1p,
               const half_t* __restrict__ W2p, const float* __restrict__ f,
               float* __restrict__ out)
{
    __shared__ half_t frag[32768];       // 64 KiB: staging aliases [0,16384); x1 full; x2 [0,16K); y3 [0,8.5K)
    __shared__ float row_m[64], row_rs[64];
    __shared__ float ps[2][64], pq[2][64];
    __shared__ half2_t w3h[64];

    const int tid  = threadIdx.x;
    const int lane = tid & 63;
    const int wv   = tid >> 6;       // wave 0..7
    const int grp  = lane >> 4;
    const int cl   = lane & 15;
    const int row  = tid >> 3;       // 0..63 (staging row)
    const int jj   = tid & 7;        // 8 threads per row
    const int rbw  = row >> 4;
    const long r0  = (long)blockIdx.x * 64;
    const float* xrow = x_in + (r0 + row) * 768;

    const int rb_s = wv & 3;         // scan row-block
    const int th_s = wv >> 2;        // scan t-half

    const float* s0f = f;        const float* c0f = f + 512;
    const float* s1f = f + 1024; const float* c1f = f + 1280;
    const float* s2f = f + 1536; const float* c2f = f + 1664;

    const half2_t one2 = {(half_t)1.f, (half_t)1.f};

    if (tid < 64) {
        half2_t w; w[0] = (half_t)f[1792 + 2 * tid]; w[1] = (half_t)f[1793 + 2 * tid];
        w3h[tid] = w;
    }

    float s = 0.f, ss = 0.f;
    f32x4 vb[4];

    auto stage_load = [&](int c) {
        const float* xp = xrow + 128 * c + 4 * jj;
        #pragma unroll
        for (int i = 0; i < 4; i++)
            vb[i] = __builtin_nontemporal_load((const f32x4*)(xp + 32 * i));
    };
    // pack to f16, stats via dot2 on the packed values, fragment ds_write
    auto stage_write = [&](int c) {
        half_t* fb = frag + 8192 * (c & 1);
        const int hg = jj >> 1, jo = 4 * (jj & 1);
        #pragma unroll
        for (int i = 0; i < 4; i++) {
            const f32x4 v = vb[i];
            half2_t h01; h01[0] = (half_t)v[0]; h01[1] = (half_t)v[1];
            half2_t h23; h23[0] = (half_t)v[2]; h23[1] = (half_t)v[3];
            s  = FDOT2(h01, one2, s);  s  = FDOT2(h23, one2, s);
            ss = FDOT2(h01, h01, ss);  ss = FDOT2(h23, h23, ss);
            half4_t hv; hv[0] = h01[0]; hv[1] = h01[1]; hv[2] = h23[0]; hv[3] = h23[1];
            *(half4_t*)(&fb[((i * 4 + rbw) * 64 + ((row & 15) + 16 * hg)) * 8 + jo]) = hv;
        }
    };

    f32x4 acc0[4][4];
    #pragma unroll
    for (int rb = 0; rb < 4; rb++)
        #pragma unroll
        for (int cb = 0; cb < 4; cb++) acc0[rb][cb] = 0.f;

    auto gemm0 = [&](int c) {
        const half_t* fb = frag + 8192 * (c & 1);
        const half_t* wp = W0p + (size_t)(4 * wv * 24 + 4 * c) * 512 + lane * 8;
        half8_t bA[4], bB[4];
        #pragma unroll
        for (int cb = 0; cb < 4; cb++) bA[cb] = *(const half8_t*)(wp + cb * 12288);
        #pragma unroll
        for (int tt = 0; tt < 4; tt++) {
            half8_t* cur = (tt & 1) ? bB : bA;
            half8_t* nxt = (tt & 1) ? bA : bB;
            if (tt < 3) {
                #pragma unroll
                for (int cb = 0; cb < 4; cb++)
                    nxt[cb] = *(const half8_t*)(wp + (tt + 1) * 512 + cb * 12288);
            }
            half8_t af[4];
            #pragma unroll
            for (int rb = 0; rb < 4; rb++)
                af[rb] = *(const half8_t*)(&fb[((tt * 4 + rb) * 64 + lane) * 8]);
            #pragma unroll
            for (int cb = 0; cb < 4; cb++)
                #pragma unroll
                for (int rb = 0; rb < 4; rb++)
                    acc0[rb][cb] = __builtin_amdgcn_mfma_f32_16x16x32_f16(af[rb], cur[cb], acc0[rb][cb], 0, 0, 0);
        }
    };

    // ---- layer-0 pipeline: 6 chunks of K=128 ----
    stage_load(0); stage_write(0);
    __syncthreads();
    #pragma unroll 1
    for (int c = 0; c < 6; c++) {
        if (c < 5) stage_load(c + 1);
        gemm0(c);
        if (c < 5) stage_write(c + 1);
        if (c == 4) {
            s  += __shfl_xor(s, 1);  s  += __shfl_xor(s, 2);  s  += __shfl_xor(s, 4);
            ss += __shfl_xor(ss, 1); ss += __shfl_xor(ss, 2); ss += __shfl_xor(ss, 4);
            if (jj == 0) {
                const float mm = s * (1.f / 768.f);
                row_m[row]  = mm;
                row_rs[row] = 1.f / sqrtf(ss * (1.f / 768.f) - mm * mm + LN_EPS);
            }
        }
        __syncthreads();
    }

    // ---- epilogue0: LN0 fold + ELU + write x1 fragments ----
    {
        float sv[4], cv[4];
        #pragma unroll
        for (int cb = 0; cb < 4; cb++) {
            const int c = cl + 16 * (4 * wv + cb);
            sv[cb] = s0f[c]; cv[cb] = c0f[c];
        }
        #pragma unroll
        for (int rb = 0; rb < 4; rb++)
            #pragma unroll
            for (int v = 0; v < 4; v++) {
                const int r = 16 * rb + 4 * grp + v;
                const float rm = row_m[r], rr = row_rs[r];
                #pragma unroll
                for (int cb = 0; cb < 4; cb++) {
                    float y = rr * (acc0[rb][cb][v] - rm * sv[cb]) + cv[cb];
                    acc0[rb][cb][v] = y > 0.f ? y : (__expf(y) - 1.f);
                }
            }
        #pragma unroll
        for (int cb = 0; cb < 4; cb++) {
            const int c = cl + 16 * (4 * wv + cb);
            const int t = c >> 5, j = c & 7, sc = 16 * ((c >> 3) & 3);
            #pragma unroll
            for (int rb = 0; rb < 4; rb++)
                #pragma unroll
                for (int v = 0; v < 4; v++)
                    frag[((t * 4 + rb) * 64 + (4 * grp + v + sc)) * 8 + j] = (half_t)acc0[rb][cb][v];
        }
    }
    __syncthreads();

    // ---- LN1 stats: conflict-free GEMM-style scan (wave covers rb_s, t-half) ----
    {
        float s_ = 0.f, q_ = 0.f;
        #pragma unroll
        for (int i = 0; i < 8; i++) {
            const int t = 8 * th_s + i;
            const half8_t h = *(const half8_t*)(&frag[((t * 4 + rb_s) * 64 + lane) * 8]);
            half2_t p0 = {h[0], h[1]}, p1 = {h[2], h[3]}, p2 = {h[4], h[5]}, p3 = {h[6], h[7]};
            s_ = FDOT2(p0, one2, s_); s_ = FDOT2(p1, one2, s_);
            s_ = FDOT2(p2, one2, s_); s_ = FDOT2(p3, one2, s_);
            q_ = FDOT2(p0, p0, q_);   q_ = FDOT2(p1, p1, q_);
            q_ = FDOT2(p2, p2, q_);   q_ = FDOT2(p3, p3, q_);
        }
        s_ += __shfl_xor(s_, 16); s_ += __shfl_xor(s_, 32);
        q_ += __shfl_xor(q_, 16); q_ += __shfl_xor(q_, 32);
        if (lane < 16) { ps[th_s][16 * rb_s + lane] = s_; pq[th_s][16 * rb_s + lane] = q_; }
    }
    __syncthreads();
    if (tid < 64) {
        const float a_ = ps[0][tid] + ps[1][tid];
        const float b_ = pq[0][tid] + pq[1][tid];
        const float mm = a_ * (1.f / 512.f);
        row_m[tid]  = mm;
        row_rs[tid] = 1.f / sqrtf(b_ * (1.f / 512.f) - mm * mm + LN_EPS);
    }

    // ---- GEMM1: K=512 (16 t-steps), wave owns 32 cols, B prefetched ----
    f32x4 acc1[4][2];
    #pragma unroll
    for (int rb = 0; rb < 4; rb++) { acc1[rb][0] = 0.f; acc1[rb][1] = 0.f; }
    {
        const half_t* wp = W1p + (size_t)(2 * wv * 16) * 512 + lane * 8;
        half8_t bA[2], bB[2];
        bA[0] = *(const half8_t*)(wp);
        bA[1] = *(const half8_t*)(wp + 8192);
        #pragma unroll
        for (int t = 0; t < 16; t++) {
            half8_t* cur = (t & 1) ? bB : bA;
            half8_t* nxt = (t & 1) ? bA : bB;
            if (t < 15) {
                nxt[0] = *(const half8_t*)(wp + (t + 1) * 512);
                nxt[1] = *(const half8_t*)(wp + (t + 1) * 512 + 8192);
            }
            half8_t af[4];
            #pragma unroll
            for (int rb = 0; rb < 4; rb++)
                af[rb] = *(const half8_t*)(&frag[((t * 4 + rb) * 64 + lane) * 8]);
            #pragma unroll
            for (int cb = 0; cb < 2; cb++)
                #pragma unroll
                for (int rb = 0; rb < 4; rb++)
                    acc1[rb][cb] = __builtin_amdgcn_mfma_f32_16x16x32_f16(af[rb], cur[cb], acc1[rb][cb], 0, 0, 0);
        }
    }
    __syncthreads();   // orders: scan-combine row_m vs ep1 reads; gemm1 frag reads vs ep1 writes

    // ---- epilogue1: LN1 fold + ELU + write x2 fragments ----
    {
        float sv[2], cv[2];
        #pragma unroll
        for (int cb = 0; cb < 2; cb++) {
            const int c = cl + 16 * (2 * wv + cb);
            sv[cb] = s1f[c]; cv[cb] = c1f[c];
        }
        #pragma unroll
        for (int rb = 0; rb < 4; rb++)
            #pragma unroll
            for (int v = 0; v < 4; v++) {
                const int r = 16 * rb + 4 * grp + v;
                const float rm = row_m[r], rr = row_rs[r];
                #pragma unroll
                for (int cb = 0; cb < 2; cb++) {
                    float y = rr * (acc1[rb][cb][v] - rm * sv[cb]) + cv[cb];
                    acc1[rb][cb][v] = y > 0.f ? y : (__expf(y) - 1.f);
                }
            }
        #pragma unroll
        for (int cb = 0; cb < 2; cb++) {
            const int c = cl + 16 * (2 * wv + cb);
            const int t = c >> 5, j = c & 7, sc = 16 * ((c >> 3) & 3);
            #pragma unroll
            for (int rb = 0; rb < 4; rb++)
                #pragma unroll
                for (int v = 0; v < 4; v++)
                    frag[((t * 4 + rb) * 64 + (4 * grp + v + sc)) * 8 + j] = (half_t)acc1[rb][cb][v];
        }
    }
    __syncthreads();

    // ---- LN2 stats: conflict-free scan of x2 (256 cols) ----
    {
        float s_ = 0.f, q_ = 0.f;
        #pragma unroll
        for (int i = 0; i < 4; i++) {
            const int t = 4 * th_s + i;
            const half8_t h = *(const half8_t*)(&frag[((t * 4 + rb_s) * 64 + lane) * 8]);
            half2_t p0 = {h[0], h[1]}, p1 = {h[2], h[3]}, p2 = {h[4], h[5]}, p3 = {h[6], h[7]};
            s_ = FDOT2(p0, one2, s_); s_ = FDOT2(p1, one2, s_);
            s_ = FDOT2(p2, one2, s_); s_ = FDOT2(p3, one2, s_);
            q_ = FDOT2(p0, p0, q_);   q_ = FDOT2(p1, p1, q_);
            q_ = FDOT2(p2, p2, q_);   q_ = FDOT2(p3, p3, q_);
        }
        s_ += __shfl_xor(s_, 16); s_ += __shfl_xor(s_, 32);
        q_ += __shfl_xor(q_, 16); q_ += __shfl_xor(q_, 32);
        if (lane < 16) { ps[th_s][16 * rb_s + lane] = s_; pq[th_s][16 * rb_s + lane] = q_; }
    }
    __syncthreads();
    if (tid < 64) {
        const float a_ = ps[0][tid] + ps[1][tid];
        const float b_ = pq[0][tid] + pq[1][tid];
        const float mm = a_ * (1.f / 256.f);
        row_m[tid]  = mm;
        row_rs[tid] = 1.f / sqrtf(b_ * (1.f / 256.f) - mm * mm + LN_EPS);
    }

    // ---- GEMM2: K=256 (8 t-steps), wave owns 16 cols ----
    f32x4 acc2[4];
    #pragma unroll
    for (int rb = 0; rb < 4; rb++) acc2[rb] = 0.f;
    {
        const half_t* wp = W2p + (size_t)(wv * 8) * 512 + lane * 8;
        half8_t bA = *(const half8_t*)(wp);
        #pragma unroll
        for (int t = 0; t < 8; t++) {
            const half8_t cur = bA;
            if (t < 7) bA = *(const half8_t*)(wp + (t + 1) * 512);
            half8_t af[4];
            #pragma unroll
            for (int rb = 0; rb < 4; rb++)
                af[rb] = *(const half8_t*)(&frag[((t * 4 + rb) * 64 + lane) * 8]);
            #pragma unroll
            for (int rb = 0; rb < 4; rb++)
                acc2[rb] = __builtin_amdgcn_mfma_f32_16x16x32_f16(af[rb], cur, acc2[rb], 0, 0, 0);
        }
    }
    __syncthreads();   // orders: LN2 combine vs ep2 reads; gemm2 frag reads vs y3 writes

    // ---- epilogue2: LN2 fold + ELU -> y3 tile [64][136] in LDS ----
    {
        const int c2i = cl + 16 * wv;
        const float sv = s2f[c2i], cv = c2f[c2i];
        #pragma unroll
        for (int rb = 0; rb < 4; rb++)
            #pragma unroll
            for (int v = 0; v < 4; v++) {
                const int r = 16 * rb + 4 * grp + v;
                const float rm = row_m[r], rr = row_rs[r];
                float y = rr * (acc2[rb][v] - rm * sv) + cv;
                y = y > 0.f ? y : (__expf(y) - 1.f);
                frag[r * 136 + c2i] = (half_t)y;
            }
    }
    __syncthreads();

    // ---- LN3 scan + folded W3 dot + output (8 threads/row, 16 cols each) ----
    {
        float s_ = 0.f, q_ = 0.f, d_ = 0.f;
        #pragma unroll
        for (int u = 0; u < 2; u++) {
            const int cb = jj * 16 + 8 * u;
            const int wi = cb >> 1;
            const half8_t h = *(const half8_t*)(frag + row * 136 + cb);
            half2_t p0 = {h[0], h[1]}, p1 = {h[2], h[3]}, p2 = {h[4], h[5]}, p3 = {h[6], h[7]};
            s_ = FDOT2(p0, one2, s_); s_ = FDOT2(p1, one2, s_);
            s_ = FDOT2(p2, one2, s_); s_ = FDOT2(p3, one2, s_);
            q_ = FDOT2(p0, p0, q_);   q_ = FDOT2(p1, p1, q_);
            q_ = FDOT2(p2, p2, q_);   q_ = FDOT2(p3, p3, q_);
            d_ = FDOT2(p0, w3h[wi], d_);     d_ = FDOT2(p1, w3h[wi + 1], d_);
            d_ = FDOT2(p2, w3h[wi + 2], d_); d_ = FDOT2(p3, w3h[wi + 3], d_);
        }
        s_ += __shfl_xor(s_, 1); s_ += __shfl_xor(s_, 2); s_ += __shfl_xor(s_, 4);
        q_ += __shfl_xor(q_, 1); q_ += __shfl_xor(q_, 2); q_ += __shfl_xor(q_, 4);
        d_ += __shfl_xor(d_, 1); d_ += __shfl_xor(d_, 2); d_ += __shfl_xor(d_, 4);
        if (jj == 0) {
            const float mm = s_ * (1.f / 128.f);
            const float rs = 1.f / sqrtf(q_ * (1.f / 128.f) - mm * mm + LN_EPS);
            out[r0 + row] = rs * (d_ - mm * f[1920]) + f[1921];
        }
    }
}

extern "C" void kernel_launch(void* const* d_in, const int* in_sizes, int n_in,
                              void* d_out, int out_size, void* d_ws, size_t ws_size,
                              hipStream_t stream) {
    const float* x  = (const float*)d_in[0];
    const float* g0 = (const float*)d_in[1];
    const float* b0 = (const float*)d_in[2];
    const float* W0 = (const float*)d_in[3];
    const float* c0 = (const float*)d_in[4];
    const float* g1 = (const float*)d_in[5];
    const float* b1 = (const float*)d_in[6];
    const float* W1 = (const float*)d_in[7];
    const float* c1 = (const float*)d_in[8];
    const float* g2 = (const float*)d_in[9];
    const float* b2 = (const float*)d_in[10];
    const float* W2 = (const float*)d_in[11];
    const float* c2 = (const float*)d_in[12];
    const float* g3 = (const float*)d_in[13];
    const float* b3 = (const float*)d_in[14];
    const float* W3 = (const float*)d_in[15];
    const float* c3 = (const float*)d_in[16];

    half_t* ws = (half_t*)d_ws;            // packed weights: 557056 halves
    float*  f  = (float*)(ws + 557056);    // folded scalars: 1922 floats

    pack_weights<<<272, 256, 0, stream>>>(W0, g0, W1, g1, W2, g2, ws);
    fold_bias<<<225, 256, 0, stream>>>(W0, g0, b0, c0, W1, g1, b1, c1,
                                       W2, g2, b2, c2, W3, g3, b3, c3, f);

    const int nrows = in_sizes[0] / 768;   // 262144
    fused_mlp<<<nrows / 64, 512, 0, stream>>>(
        x, ws, ws + 393216, ws + 524288, f, (float*)d_out);
}